// Round 11
// baseline (7101.561 us; speedup 1.0000x reference)
//
#include <hip/hip_runtime.h>
#include <hip/hip_bf16.h>
#include <math.h>

typedef __hip_bfloat16 bf16;

#define NPTS  8192
#define BATCH 2
#define KNB   16
#define NPART 4
#define PARTC (NPTS / NPART)   // 2048
#define CAP   24               // knn pass-2 capture buffer per thread
#define LSTR  69               // k_feat per-thread LDS slice stride
#define BN    (BATCH * NPTS)

#define C_IE 0.9999950000374997f   // 1/sqrt(1+1e-5)
#define C_PM 0.9995003746877732f   // 1/sqrt(1+1e-3)

// ---- weight block float offsets inside ws ----
enum {
  WOFF_CW1A = 0,     WOFF_CB1A = 8192,  WOFF_CW1B = 8256,  WOFF_CB1B = 12352,
  WOFF_CW2A = 12416, WOFF_CB2A = 20608, WOFF_CW2B = 20672, WOFF_CB2B = 24768,
  WOFF_CW3A = 24832, WOFF_CB3A = 29120, WOFF_CW3B = 29184, WOFF_CB3B = 33280,
  WOFF_CW4A = 33344, WOFF_CB4A = 41536, WOFF_CW4B = 41600, WOFF_CB4B = 45696,
  WOFF_IEW1 = 45760, WOFF_IEB1 = 45952, WOFF_IEG  = 46016, WOFF_IEBT = 46080,
  WOFF_IEW2 = 46144, WOFF_IEB2 = 50240, WOFF_PECW = 50304, WOFF_PECB = 51840,
  WOFF_PMW1 = 51904, WOFF_PMB1 = 56000, WOFF_PMG1 = 56064, WOFF_PMT1 = 56128,
  WOFF_PMW2 = 56192, WOFF_PMB2 = 60288, WOFF_PMG2 = 60352, WOFF_PMT2 = 60416,
  WOFF_PMW3 = 60480, WOFF_PMB3 = 62528, WOFF_PMG3 = 62560, WOFF_PMT3 = 62592,
  WOFF_PMW4 = 62624, WOFF_PMB4 = 62656, WOFF_PMG4 = 62657, WOFF_PMT4 = 62658
};

// LDS staging layout for k_logit (floats)
#define LW_IE2 0
#define LW_PM1 4096
#define LW_PM2 8192
#define LW_PM3 12288
#define LW_PEC 14336
#define LW_TOT 15872   // 63,488 B static LDS

// ---- ws byte offsets (end 13,893,648 B == round-6..8 footprint, known good) ----
#define BOFF_W    0u
#define BOFF_FLAG 262144u
#define BOFF_PK   262160u     // 4 x [B*N] float4 (2 MB)
#define BOFF_IDX  2359312u    // final idx [2][B][N][16] i32 (2 MB)
#define BOFF_AW   4456464u    // attention weights u16 [2][B][N][16] (1 MB)
#define BOFF_P1T  5505040u    // points1^T [B][N][64] f32 (4 MB)
#define BOFF_P2T  9699344u    // points2^T [B][N][64] f32 (4 MB)
#define BOFF_PART BOFF_P1T    // knn partials aliased over P1T/P2T; k_tr after k_merge

__device__ __forceinline__ float lrelu(float v) { return v > 0.f ? v : 0.1f * v; }

__device__ __forceinline__ float ldin(const void* p, size_t i, int f32) {
  return f32 ? ((const float*)p)[i] : __bfloat162float(((const bf16*)p)[i]);
}
__device__ __forceinline__ void stout(void* p, size_t i, float v, int f32) {
  if (f32) ((float*)p)[i] = v;
  else ((bf16*)p)[i] = __float2bfloat16(v);
}

// opaque per-lane zero -> forces vector (global_load) addressing of weights,
// pipelined via in-order vmcnt (s_load serializes -- r9 lesson).
__device__ __forceinline__ int vzero() {
  int vz;
  asm volatile("v_mov_b32 %0, 0" : "=v"(vz));
  return vz;
}

// dense layer: input in LDS slice, weights via broadcast vector loads (r8, k_feat)
template<int IN, int OUT>
__device__ __forceinline__ void layer_gv(const float* __restrict__ Wg,
                                         const float* __restrict__ bias,
                                         const float* sIn, float* acc, int vz) {
#pragma unroll
  for (int j = 0; j < OUT; ++j) acc[j] = bias[j];
  const float4* w4 = (const float4*)Wg + vz;
#pragma unroll 2
  for (int i = 0; i < IN; ++i) {
    float x = sIn[i];
#pragma unroll
    for (int jj = 0; jj < OUT / 4; ++jj) {
      float4 wv = w4[i * (OUT / 4) + jj];
      acc[4 * jj + 0] = fmaf(x, wv.x, acc[4 * jj + 0]);
      acc[4 * jj + 1] = fmaf(x, wv.y, acc[4 * jj + 1]);
      acc[4 * jj + 2] = fmaf(x, wv.z, acc[4 * jj + 2]);
      acc[4 * jj + 3] = fmaf(x, wv.w, acc[4 * jj + 3]);
    }
  }
}

// dense layer: x in REGISTERS (fully unrolled -> constant indices), weights in LDS
template<int IN, int OUT>
__device__ __forceinline__ void layer_lw(const float* lw,           // LDS weights
                                         const float* __restrict__ bias,  // global
                                         const float* __restrict__ x,     // regs
                                         float* __restrict__ acc) {
#pragma unroll
  for (int j = 0; j < OUT; ++j) acc[j] = bias[j];
#pragma unroll
  for (int i = 0; i < IN; ++i) {
    const float4* w4 = (const float4*)(lw + i * OUT);
#pragma unroll
    for (int jj = 0; jj < OUT / 4; ++jj) {
      float4 wv = w4[jj];
      acc[4 * jj + 0] = fmaf(x[i], wv.x, acc[4 * jj + 0]);
      acc[4 * jj + 1] = fmaf(x[i], wv.y, acc[4 * jj + 1]);
      acc[4 * jj + 2] = fmaf(x[i], wv.z, acc[4 * jj + 2]);
      acc[4 * jj + 3] = fmaf(x[i], wv.w, acc[4 * jj + 3]);
    }
  }
}

// stable top-16 insertion (keeps lower index on ties when fed ascending j)
__device__ __forceinline__ void insert16(float d, int id, float* best, int* bidx) {
#pragma unroll
  for (int p = 0; p < KNB; ++p) {
    bool c = d < best[p];
    float tb = best[p]; int ti = bidx[p];
    best[p] = c ? d : tb; bidx[p] = c ? id : ti;
    d = c ? tb : d; id = c ? ti : id;
  }
}

// exact reference distance chain (bit-replicates f32 expanded form)
__device__ __forceinline__ float qsq(float4 qv) {
  return __fadd_rn(__fadd_rn(__fmul_rn(qv.x, qv.x), __fmul_rn(qv.y, qv.y)),
                   __fmul_rn(qv.z, qv.z));
}
__device__ __forceinline__ float refdist(float4 qv, float sq, float4 rv) {
  float sr = qsq(rv);
  float dot = __fmaf_rn(qv.z, rv.z, __fmaf_rn(qv.y, rv.y, __fmul_rn(qv.x, rv.x)));
  return __fsub_rn(__fadd_rn(sq, sr), __fadd_rn(dot, dot));
}
__device__ __forceinline__ float refdist_sr(float4 qv, float sq, float4 rv) {
  float dot = __fmaf_rn(qv.z, rv.z, __fmaf_rn(qv.y, rv.y, __fmul_rn(qv.x, rv.x)));
  return __fsub_rn(__fadd_rn(sq, rv.w), __fadd_rn(dot, dot));
}

// ---------------- dtype autodetect ----------------
__global__ void k_detect(const void* __restrict__ pts1, int* __restrict__ flag) {
  int tid = threadIdx.x;  // 64
  const bf16* p = (const bf16*)pts1;
  int cnt = 0;
  for (int i = tid; i < 1024; i += 64) {
    float v = __bfloat162float(p[i]);
    if (!(fabsf(v) <= 64.f)) cnt++;
  }
#pragma unroll
  for (int s = 32; s; s >>= 1) cnt += __shfl_down(cnt, s);
  if (tid == 0) *flag = (cnt >= 8) ? 1 : 0;
}

// ---------------- prep ----------------
struct PrepTab {
  const void* src[40];
  int off[40];
  int n[40];
  float scale[40];
};

__global__ void k_prep(PrepTab tab, float* __restrict__ W, const int* __restrict__ flag) {
  int f32 = *flag;
  int a = blockIdx.x;
  const void* s = tab.src[a];
  float* d = W + tab.off[a];
  float sc = tab.scale[a];
  for (int i = threadIdx.x; i < tab.n[a]; i += blockDim.x) d[i] = ldin(s, i, f32) * sc;
}

// ---------------- pack ----------------
__global__ void k_pack(const void* __restrict__ xyz1, const void* __restrict__ xyz2,
                       const void* __restrict__ xyz2w, const void* __restrict__ sf,
                       float4* __restrict__ pk, const int* __restrict__ flag) {
  int f32 = *flag;
  int t = blockIdx.x * 256 + threadIdx.x;  // B*N
  int b = t >> 13, n = t & (NPTS - 1);
  size_t base = (size_t)b * 3 * NPTS + n;
  float ax = ldin(xyz1, base, f32), ay = ldin(xyz1, base + NPTS, f32), az = ldin(xyz1, base + 2 * NPTS, f32);
  float sx = ldin(sf, base, f32),   sy = ldin(sf, base + NPTS, f32),   sz = ldin(sf, base + 2 * NPTS, f32);
  pk[t]          = make_float4(__fadd_rn(ax, sx), __fadd_rn(ay, sy), __fadd_rn(az, sz), 0.f);
  pk[t + BN]     = make_float4(ax, ay, az, 0.f);
  pk[t + 2 * BN] = make_float4(ldin(xyz2, base, f32), ldin(xyz2, base + NPTS, f32), ldin(xyz2, base + 2 * NPTS, f32), 0.f);
  pk[t + 3 * BN] = make_float4(ldin(xyz2w, base, f32), ldin(xyz2w, base + NPTS, f32), ldin(xyz2w, base + 2 * NPTS, f32), 0.f);
}

// ---------------- transpose ----------------
__global__ __launch_bounds__(64) void k_tr(const void* __restrict__ src, float* __restrict__ dst,
                                           const int* __restrict__ flag) {
  __shared__ float tile[64][65];
  int f32 = *flag;
  int tid = threadIdx.x;
  int n0 = blockIdx.x * 64;
  int b = blockIdx.y;
  for (int i = 0; i < 64; ++i)
    tile[i][tid] = ldin(src, ((size_t)b * 64 + i) * NPTS + n0 + tid, f32);
  __syncthreads();
  for (int i = 0; i < 64; ++i)
    dst[((size_t)b * NPTS + n0 + i) * 64 + tid] = tile[tid][i];
}

// ---------------- KNN partials: 3-phase exact top-16 ----------------
__global__ __launch_bounds__(64) void k_knnp(const float4* __restrict__ pk,
                                             int* __restrict__ part_idx) {
  __shared__ float4 tile[64];
  __shared__ int sbuf[64 * CAP];
  int tid = threadIdx.x;
  int n = blockIdx.x * 64 + tid;
  int b = blockIdx.y;
  int which = blockIdx.z >> 2;
  int part  = blockIdx.z & 3;
  const float4* q = pk + (size_t)which * BN;
  const float4* r = pk + (size_t)(2 + which) * BN + (size_t)b * NPTS;
  float4 qv = q[b * NPTS + n];
  float sq = qsq(qv);

  float best[KNB];
#pragma unroll
  for (int p = 0; p < KNB; ++p) best[p] = 3.4e38f;

  int t0 = part * (PARTC / 64);
  for (int t = t0; t < t0 + PARTC / 64; ++t) {
    __syncthreads();
    {
      float4 rv = r[t * 64 + tid];
      rv.w = qsq(rv);
      tile[tid] = rv;
    }
    __syncthreads();
#pragma unroll 8
    for (int jj = 0; jj < 64; ++jj) {
      float dd = refdist_sr(qv, sq, tile[jj]);
#pragma unroll
      for (int p = 0; p < KNB; ++p) {
        float mx = fmaxf(dd, best[p]);
        best[p] = fminf(dd, best[p]);
        dd = mx;
      }
    }
  }
  float thr = best[KNB - 1];

  int cnt = 0;
  for (int t = t0; t < t0 + PARTC / 64; ++t) {
    __syncthreads();
    {
      float4 rv = r[t * 64 + tid];
      rv.w = qsq(rv);
      tile[tid] = rv;
    }
    __syncthreads();
#pragma unroll 8
    for (int jj = 0; jj < 64; ++jj) {
      float dd = refdist_sr(qv, sq, tile[jj]);
      if (dd <= thr && cnt < CAP) {
        sbuf[tid * CAP + cnt] = t * 64 + jj;
        cnt++;
      }
    }
  }

  float bd[KNB]; int bi[KNB];
#pragma unroll
  for (int p = 0; p < KNB; ++p) { bd[p] = 3.4e38f; bi[p] = 0; }
  for (int m = 0; m < CAP; ++m) {
    if (m < cnt) {
      int id = sbuf[tid * CAP + m];
      float dd = refdist(qv, sq, r[id]);
      insert16(dd, id, bd, bi);
    }
  }
  size_t o = ((((size_t)which * BATCH + b) * NPART + part) * NPTS + n) * KNB;
#pragma unroll
  for (int p = 0; p < KNB; ++p) part_idx[o + p] = bi[p];
}

// ---------------- KNN merge ----------------
__global__ void k_merge(const float4* __restrict__ pk, const int* __restrict__ part_idx,
                        int* __restrict__ idxf) {
  int t = blockIdx.x * 256 + threadIdx.x;
  int n = t & (NPTS - 1);
  int wb = t >> 13;
  int b = wb & (BATCH - 1);
  int which = wb / BATCH;
  const float4* q = pk + (size_t)which * BN;
  const float4* r = pk + (size_t)(2 + which) * BN + (size_t)b * NPTS;
  float4 qv = q[b * NPTS + n];
  float sq = qsq(qv);
  float best[KNB]; int bidx[KNB];
#pragma unroll
  for (int p = 0; p < KNB; ++p) { best[p] = 3.4e38f; bidx[p] = 0; }
  for (int part = 0; part < NPART; ++part) {
    size_t o = ((((size_t)which * BATCH + b) * NPART + part) * NPTS + n) * KNB;
#pragma unroll
    for (int m = 0; m < KNB; ++m) {
      int id = part_idx[o + m];
      float dd = refdist(qv, sq, r[id]);
      if (dd < best[KNB - 1]) insert16(dd, id, best, bidx);
    }
  }
  size_t oo = (size_t)t * KNB;
#pragma unroll
  for (int p = 0; p < KNB; ++p) idxf[oo + p] = bidx[p];
}

// ---------------- IPC logit: x in registers, big weights from LDS ----------------
__device__ __forceinline__ float ipc_logit_lds(const float* __restrict__ W,
                                               const float* sw,
                                               float pdx, float pdy, float pdz) {
  float xa[64], xb[64];
  // ie1: 3 -> 64 (global W, small, once)
  {
    const float* w = W + WOFF_IEW1;
    const float* bb = W + WOFF_IEB1;
    const float* g = W + WOFF_IEG;
    const float* bt = W + WOFF_IEBT;
#pragma unroll
    for (int j = 0; j < 64; ++j) {
      float v = bb[j];
      v = fmaf(pdx, w[j], v);
      v = fmaf(pdy, w[64 + j], v);
      v = fmaf(pdz, w[128 + j], v);
      v = fmaf(v, g[j], bt[j]);
      xa[j] = fmaxf(v, 0.f);
    }
  }
  layer_lw<64, 64>(sw + LW_IE2, W + WOFF_IEB2, xa, xb);
  // PEC add (weights from LDS)
  {
    const float* pb = W + WOFF_PECB;
#pragma unroll
    for (int j = 0; j < 64; ++j) xb[j] += pb[j];
    float pe[3];
    pe[0] = (pdx - rintf(pdx * 4.f) * 0.25f) * 4.f;
    pe[1] = (pdy - rintf(pdy * 4.f) * 0.25f) * 4.f;
    pe[2] = (pdz - rintf(pdz * 4.f) * 0.25f) * 4.f;
#pragma unroll
    for (int c = 0; c < 3; ++c) {
      float tt = pe[c] / 1.000001f * 6.28318530717958647692f;
#pragma unroll
      for (int f = 0; f < 4; ++f) {
        float dv = (f == 0) ? 1.f : (f == 1) ? 10.f : (f == 2) ? 100.f : 1000.f;
        float a = tt / dv;
        float sn, cs;
        sincosf(a, &sn, &cs);
        const float* ws = sw + LW_PEC + (c * 8 + f * 2) * 64;
        const float* wc = sw + LW_PEC + (c * 8 + f * 2 + 1) * 64;
#pragma unroll
        for (int j = 0; j < 64; ++j) xb[j] = fmaf(sn, ws[j], xb[j]);
#pragma unroll
        for (int j = 0; j < 64; ++j) xb[j] = fmaf(cs, wc[j], xb[j]);
      }
    }
  }
  layer_lw<64, 64>(sw + LW_PM1, W + WOFF_PMB1, xb, xa);
  {
    const float* g = W + WOFF_PMG1; const float* bt = W + WOFF_PMT1;
#pragma unroll
    for (int j = 0; j < 64; ++j) xa[j] = fmaxf(fmaf(xa[j], g[j], bt[j]), 0.f);
  }
  layer_lw<64, 64>(sw + LW_PM2, W + WOFF_PMB2, xa, xb);
  {
    const float* g = W + WOFF_PMG2; const float* bt = W + WOFF_PMT2;
#pragma unroll
    for (int j = 0; j < 64; ++j) xb[j] = fmaxf(fmaf(xb[j], g[j], bt[j]), 0.f);
  }
  layer_lw<64, 32>(sw + LW_PM3, W + WOFF_PMB3, xb, xa);
  {
    const float* g = W + WOFF_PMG3; const float* bt = W + WOFF_PMT3;
#pragma unroll
    for (int j = 0; j < 32; ++j) xa[j] = fmaf(xa[j], g[j], bt[j]);
  }
  const float* w4 = W + WOFF_PMW4;
  float l = W[WOFF_PMB4];
#pragma unroll
  for (int i = 0; i < 32; ++i) l = fmaf(xa[i], w4[i], l);
  return fmaf(l, W[WOFF_PMG4], W[WOFF_PMT4]);
}

// ---------------- k_logit: stage weights -> LDS, IPC + softmax -> u16 ----------------
// block = 256 threads = 16 points x 16 neighbors; which = blockIdx.y.
__global__ __launch_bounds__(256, 2) void k_logit(const float* __restrict__ W,
                                                  const int* __restrict__ idxf,
                                                  const float4* __restrict__ pk,
                                                  unsigned short* __restrict__ AW) {
  __shared__ float sw[LW_TOT];   // 63,488 B
  int tid = threadIdx.x;
  // stage big weight matrices (float4 copies; all offsets 16B-aligned)
  {
    float4* d4 = (float4*)sw;
    const float4* s_ie2 = (const float4*)(W + WOFF_IEW2);
    const float4* s_pm1 = (const float4*)(W + WOFF_PMW1);
    const float4* s_pm2 = (const float4*)(W + WOFF_PMW2);
    const float4* s_pm3 = (const float4*)(W + WOFF_PMW3);
    const float4* s_pec = (const float4*)(W + WOFF_PECW);
    for (int i = tid; i < 1024; i += 256) {
      d4[LW_IE2 / 4 + i] = s_ie2[i];
      d4[LW_PM1 / 4 + i] = s_pm1[i];
      d4[LW_PM2 / 4 + i] = s_pm2[i];
    }
    for (int i = tid; i < 512; i += 256) d4[LW_PM3 / 4 + i] = s_pm3[i];
    for (int i = tid; i < 384; i += 256) d4[LW_PEC / 4 + i] = s_pec[i];
  }
  __syncthreads();

  int k = tid & (KNB - 1);
  int p = tid >> 4;                // 0..15
  int which = blockIdx.y;
  int pt = blockIdx.x * 16 + p;    // b*N+n
  int n = pt & (NPTS - 1);
  int b = pt >> 13;
  int idxv = idxf[(((size_t)which * BATCH + b) * NPTS + n) * KNB + k];
  float4 pv = pk[(size_t)2 * BN + (size_t)b * NPTS + idxv];  // x2[idx]
  float4 qp = pk[(size_t)BN + pt];                           // x1[n]
  float l = ipc_logit_lds(W, sw, pv.x - qp.x, pv.y - qp.y, pv.z - qp.z);

  float m = l;
#pragma unroll
  for (int s = 1; s < KNB; s <<= 1) m = fmaxf(m, __shfl_xor(m, s, KNB));
  float e = expf(l - m);
  float ssum = e;
#pragma unroll
  for (int s = 1; s < KNB; s <<= 1) ssum += __shfl_xor(ssum, s, KNB);
  float aw = e / ssum;
  AW[(((size_t)which * BATCH + b) * NPTS + n) * KNB + k] =
      (unsigned short)__float2uint_rn(aw * 65535.f);
}

// ---------------- k_feat: r8 structure (LDS slices + vz vector weights) ----------------
__global__ __launch_bounds__(128) void k_feat(const float* __restrict__ P1T,
                                              const float* __restrict__ P2T,
                                              const float* __restrict__ W,
                                              const int* __restrict__ idxf,
                                              const unsigned short* __restrict__ AW,
                                              const float4* __restrict__ pk,
                                              void* __restrict__ out,
                                              const int* __restrict__ flag) {
  __shared__ float sb[128 * LSTR];   // sU/sC aliased below (phases barrier-disjoint)
  float* sT = sb + (int)threadIdx.x * LSTR;
  float* sC = sb;                    // [8][132]
  float* sU = sb + 1056;             // [8][68]
  int vz = vzero();
  int f32 = *flag;
  int k = threadIdx.x & (KNB - 1);
  int p = threadIdx.x >> 4;
  int pt = blockIdx.x * 8 + p;       // b*N+n
  int n = pt & (NPTS - 1);
  int b = pt >> 13;
  float4 qp = pk[(size_t)BN + pt];   // x1[n]

  float cost[8];

  for (int which = 0; which < 2; ++which) {
    int idxv = idxf[(((size_t)which * BATCH + b) * NPTS + n) * KNB + k];
    float4 pv = pk[(size_t)2 * BN + (size_t)b * NPTS + idxv];  // x2[idx]
    float pdx = pv.x - qp.x, pdy = pv.y - qp.y, pdz = pv.z - qp.z;
    float aw = (float)AW[(((size_t)which * BATCH + b) * NPTS + n) * KNB + k] *
               (1.f / 65535.f);

    // ---- gp1 partial: lane computes channels k*4..k*4+3 ----
    {
      const float* Wa = W + (which == 0 ? WOFF_CW1A : WOFF_CW2A);
      const float* Ba = W + (which == 0 ? WOFF_CB1A : WOFF_CB2A);
      float u0 = Ba[k * 4 + 0], u1 = Ba[k * 4 + 1], u2 = Ba[k * 4 + 2], u3 = Ba[k * 4 + 3];
      const float4* p1r = (const float4*)(P1T + ((size_t)b * NPTS + n) * 64);
#define USTEP(XC, II) { float x = (XC); const float* w = Wa + (II) * 64 + k * 4; \
      u0 = fmaf(x, w[0], u0); u1 = fmaf(x, w[1], u1); \
      u2 = fmaf(x, w[2], u2); u3 = fmaf(x, w[3], u3); }
      for (int i4 = 0; i4 < 16; ++i4) {
        float4 x4 = p1r[i4];
        USTEP(x4.x, i4 * 4 + 0) USTEP(x4.y, i4 * 4 + 1)
        USTEP(x4.z, i4 * 4 + 2) USTEP(x4.w, i4 * 4 + 3)
      }
#undef USTEP
      sU[p * 68 + k * 4 + 0] = u0; sU[p * 68 + k * 4 + 1] = u1;
      sU[p * 68 + k * 4 + 2] = u2; sU[p * 68 + k * 4 + 3] = u3;
    }
    __syncthreads();

    float acc[64];
#pragma unroll
    for (int j = 0; j < 64; ++j) acc[j] = sU[p * 68 + j];
    __syncthreads();   // sU aliased into sb: consume before sT writes

    // ---- gp2 side of layer-a: broadcast vector-load weights ----
    {
      const float4* w4a = (const float4*)(W + (which == 0 ? WOFF_CW1A : WOFF_CW2A) + 64 * 64) + vz;
      const float4* p2r = (const float4*)(P2T + ((size_t)b * NPTS + idxv) * 64);
#define GSTEP(XC, II) { float x = (XC); \
      _Pragma("unroll") for (int jj = 0; jj < 16; ++jj) { \
        float4 wv = w4a[(II) * 16 + jj]; \
        acc[4 * jj + 0] = fmaf(x, wv.x, acc[4 * jj + 0]); \
        acc[4 * jj + 1] = fmaf(x, wv.y, acc[4 * jj + 1]); \
        acc[4 * jj + 2] = fmaf(x, wv.z, acc[4 * jj + 2]); \
        acc[4 * jj + 3] = fmaf(x, wv.w, acc[4 * jj + 3]); } }
      for (int i4 = 0; i4 < 16; ++i4) {
        float4 x4 = p2r[i4];
        GSTEP(x4.x, i4 * 4 + 0) GSTEP(x4.y, i4 * 4 + 1)
        GSTEP(x4.z, i4 * 4 + 2) GSTEP(x4.w, i4 * 4 + 3)
      }
#undef GSTEP
    }
#pragma unroll
    for (int j = 0; j < 64; ++j) sT[j] = lrelu(acc[j]);
    if (which == 0) {
      layer_gv<64, 64>(W + WOFF_CW1B, W + WOFF_CB1B, sT, acc, vz);
    } else {
      layer_gv<64, 64>(W + WOFF_CW2B, W + WOFF_CB2B, sT, acc, vz);
      sT[0] = pdx; sT[1] = pdy; sT[2] = pdz;
#pragma unroll
      for (int j = 0; j < 64; ++j) sT[3 + j] = lrelu(acc[j]);
      layer_gv<67, 64>(W + WOFF_CW3A, W + WOFF_CB3A, sT, acc, vz);
#pragma unroll
      for (int j = 0; j < 64; ++j) sT[j] = lrelu(acc[j]);
      layer_gv<64, 64>(W + WOFF_CW3B, W + WOFF_CB3B, sT, acc, vz);
    }

    // ---- scaled row to LDS, transpose-reduce over the 16 neighbors ----
#pragma unroll
    for (int j = 0; j < 64; ++j) sT[j] = lrelu(acc[j]) * aw;
    __syncthreads();
    float o0 = 0.f, o1 = 0.f, o2 = 0.f, o3 = 0.f;
#pragma unroll
    for (int kk = 0; kk < KNB; ++kk) {
      const float* row = sb + (p * KNB + kk) * LSTR + k * 4;
      o0 += row[0]; o1 += row[1]; o2 += row[2]; o3 += row[3];
    }
    cost[which * 4 + 0] = o0; cost[which * 4 + 1] = o1;
    cost[which * 4 + 2] = o2; cost[which * 4 + 3] = o3;
    __syncthreads();
  }

  // ---- chain4: [costA | costB] -> 64 -> 64 ----
#pragma unroll
  for (int q = 0; q < 4; ++q) {
    sC[p * 132 + k * 4 + q] = cost[q];
    sC[p * 132 + 64 + k * 4 + q] = cost[4 + q];
  }
  __syncthreads();
  float a4[4];
  {
    const float* W4 = W + WOFF_CW4A;
    const float* B4 = W + WOFF_CB4A;
#pragma unroll
    for (int q = 0; q < 4; ++q) a4[q] = B4[k * 4 + q];
    for (int i = 0; i < 128; ++i) {
      float x = sC[p * 132 + i];
      const float* w = W4 + i * 64 + k * 4;
#pragma unroll
      for (int q = 0; q < 4; ++q) a4[q] = fmaf(x, w[q], a4[q]);
    }
  }
  __syncthreads();
#pragma unroll
  for (int q = 0; q < 4; ++q) sU[p * 68 + k * 4 + q] = lrelu(a4[q]);
  __syncthreads();
  {
    const float* W4 = W + WOFF_CW4B;
    const float* B4 = W + WOFF_CB4B;
#pragma unroll
    for (int q = 0; q < 4; ++q) a4[q] = B4[k * 4 + q];
    for (int i = 0; i < 64; ++i) {
      float x = sU[p * 68 + i];
      const float* w = W4 + i * 64 + k * 4;
#pragma unroll
      for (int q = 0; q < 4; ++q) a4[q] = fmaf(x, w[q], a4[q]);
    }
  }
  size_t ob = (size_t)b * 64 * NPTS + n;
#pragma unroll
  for (int q = 0; q < 4; ++q)
    stout(out, ob + (size_t)(k * 4 + q) * NPTS, lrelu(a4[q]), f32);
}

// ---------------- host ----------------
extern "C" void kernel_launch(void* const* d_in, const int* in_sizes, int n_in,
                              void* d_out, int out_size, void* d_ws, size_t ws_size,
                              hipStream_t stream) {
  (void)in_sizes; (void)n_in; (void)out_size; (void)ws_size;
  float*  W    = (float*)d_ws;
  int*    FLAG = (int*)((char*)d_ws + BOFF_FLAG);
  float4* PK   = (float4*)((char*)d_ws + BOFF_PK);
  int*    IDX  = (int*)((char*)d_ws + BOFF_IDX);
  unsigned short* AW = (unsigned short*)((char*)d_ws + BOFF_AW);
  float*  P1T  = (float*)((char*)d_ws + BOFF_P1T);
  float*  P2T  = (float*)((char*)d_ws + BOFF_P2T);
  int*    PART = (int*)((char*)d_ws + BOFF_PART);

  static const int WOFFS[40] = {
    WOFF_CW1A, WOFF_CB1A, WOFF_CW1B, WOFF_CB1B,
    WOFF_CW2A, WOFF_CB2A, WOFF_CW2B, WOFF_CB2B,
    WOFF_CW3A, WOFF_CB3A, WOFF_CW3B, WOFF_CB3B,
    WOFF_CW4A, WOFF_CB4A, WOFF_CW4B, WOFF_CB4B,
    WOFF_IEW1, WOFF_IEB1, WOFF_IEG,  WOFF_IEBT,
    WOFF_IEW2, WOFF_IEB2, WOFF_PECW, WOFF_PECB,
    WOFF_PMW1, WOFF_PMB1, WOFF_PMG1, WOFF_PMT1,
    WOFF_PMW2, WOFF_PMB2, WOFF_PMG2, WOFF_PMT2,
    WOFF_PMW3, WOFF_PMB3, WOFF_PMG3, WOFF_PMT3,
    WOFF_PMW4, WOFF_PMB4, WOFF_PMG4, WOFF_PMT4};
  static const int WNS[40] = {
    8192, 64, 4096, 64,  8192, 64, 4096, 64,  4288, 64, 4096, 64,
    8192, 64, 4096, 64,  192, 64, 64, 64,  4096, 64,  1536, 64,
    4096, 64, 64, 64,  4096, 64, 64, 64,  2048, 32, 32, 32,  32, 1, 1, 1};

  PrepTab tab;
  for (int a = 0; a < 40; ++a) {
    tab.src[a] = d_in[6 + a];
    tab.off[a] = WOFFS[a];
    tab.n[a] = WNS[a];
    tab.scale[a] = 1.f;
  }
  tab.scale[18] = C_IE;                               // ie_g
  tab.scale[26] = C_PM; tab.scale[30] = C_PM;         // pm_g1, pm_g2
  tab.scale[34] = C_PM; tab.scale[38] = C_PM;         // pm_g3, pm_g4

  k_detect<<<dim3(1), dim3(64), 0, stream>>>(d_in[3], FLAG);
  k_prep<<<dim3(40), dim3(256), 0, stream>>>(tab, W, FLAG);
  k_pack<<<dim3(64), dim3(256), 0, stream>>>(d_in[0], d_in[1], d_in[2], d_in[5], PK, FLAG);
  k_knnp<<<dim3(NPTS / 64, BATCH, 2 * NPART), dim3(64), 0, stream>>>(PK, PART);
  k_merge<<<dim3(2 * BN / 256), dim3(256), 0, stream>>>(PK, PART, IDX);
  // transposes AFTER merge: PART aliases P1T/P2T
  k_tr<<<dim3(NPTS / 64, BATCH), dim3(64), 0, stream>>>(d_in[3], P1T, FLAG);
  k_tr<<<dim3(NPTS / 64, BATCH), dim3(64), 0, stream>>>(d_in[4], P2T, FLAG);
  k_logit<<<dim3(BN / 16, 2), dim3(256), 0, stream>>>(W, IDX, PK, AW);
  k_feat<<<dim3(BN / 8), dim3(128), 0, stream>>>(P1T, P2T, W, IDX, AW, PK, d_out, FLAG);
}

// Round 12
// 3304.206 us; speedup vs baseline: 2.1492x; 2.1492x over previous
//
#include <hip/hip_runtime.h>
#include <hip/hip_bf16.h>
#include <math.h>

typedef __hip_bfloat16 bf16;

#define NPTS  8192
#define BATCH 2
#define KNB   16
#define NPART 4
#define PARTC (NPTS / NPART)   // 2048
#define CAP   24               // knn pass-2 capture buffer per thread
#define LSTR  69               // k_feat per-thread LDS slice stride
#define BN    (BATCH * NPTS)

#define C_IE 0.9999950000374997f   // 1/sqrt(1+1e-5)
#define C_PM 0.9995003746877732f   // 1/sqrt(1+1e-3)

// ---- weight block float offsets inside ws ----
enum {
  WOFF_CW1A = 0,     WOFF_CB1A = 8192,  WOFF_CW1B = 8256,  WOFF_CB1B = 12352,
  WOFF_CW2A = 12416, WOFF_CB2A = 20608, WOFF_CW2B = 20672, WOFF_CB2B = 24768,
  WOFF_CW3A = 24832, WOFF_CB3A = 29120, WOFF_CW3B = 29184, WOFF_CB3B = 33280,
  WOFF_CW4A = 33344, WOFF_CB4A = 41536, WOFF_CW4B = 41600, WOFF_CB4B = 45696,
  WOFF_IEW1 = 45760, WOFF_IEB1 = 45952, WOFF_IEG  = 46016, WOFF_IEBT = 46080,
  WOFF_IEW2 = 46144, WOFF_IEB2 = 50240, WOFF_PECW = 50304, WOFF_PECB = 51840,
  WOFF_PMW1 = 51904, WOFF_PMB1 = 56000, WOFF_PMG1 = 56064, WOFF_PMT1 = 56128,
  WOFF_PMW2 = 56192, WOFF_PMB2 = 60288, WOFF_PMG2 = 60352, WOFF_PMT2 = 60416,
  WOFF_PMW3 = 60480, WOFF_PMB3 = 62528, WOFF_PMG3 = 62560, WOFF_PMT3 = 62592,
  WOFF_PMW4 = 62624, WOFF_PMB4 = 62656, WOFF_PMG4 = 62657, WOFF_PMT4 = 62658
};

// LDS staging layout for k_logit weights (floats)
#define LW_IE2 0
#define LW_PM1 4096
#define LW_PM2 8192
#define LW_PM3 12288
#define LW_PEC 14336
#define LW_TOT 15872   // 63,488 B

// ---- ws byte offsets (end 13,893,648 B == round-6..8 footprint, known good) ----
#define BOFF_W    0u
#define BOFF_FLAG 262144u
#define BOFF_PK   262160u     // 4 x [B*N] float4 (2 MB)
#define BOFF_IDX  2359312u    // final idx [2][B][N][16] i32 (2 MB)
#define BOFF_AW   4456464u    // attention weights u16 [2][B][N][16] (1 MB)
#define BOFF_P1T  5505040u    // points1^T [B][N][64] f32 (4 MB)
#define BOFF_P2T  9699344u    // points2^T [B][N][64] f32 (4 MB)
#define BOFF_PART BOFF_P1T    // knn partials aliased over P1T/P2T; k_tr after k_merge

__device__ __forceinline__ float lrelu(float v) { return v > 0.f ? v : 0.1f * v; }

__device__ __forceinline__ float ldin(const void* p, size_t i, int f32) {
  return f32 ? ((const float*)p)[i] : __bfloat162float(((const bf16*)p)[i]);
}
__device__ __forceinline__ void stout(void* p, size_t i, float v, int f32) {
  if (f32) ((float*)p)[i] = v;
  else ((bf16*)p)[i] = __float2bfloat16(v);
}

// opaque per-lane zero -> forces vector (global_load) addressing of weights,
// pipelined via in-order vmcnt (s_load serializes -- r9 lesson).
__device__ __forceinline__ int vzero() {
  int vz;
  asm volatile("v_mov_b32 %0, 0" : "=v"(vz));
  return vz;
}

// dense layer: input in LDS slice, weights via broadcast GLOBAL vector loads (r8)
template<int IN, int OUT>
__device__ __forceinline__ void layer_gv(const float* __restrict__ Wg,
                                         const float* __restrict__ bias,
                                         const float* sIn, float* acc, int vz) {
#pragma unroll
  for (int j = 0; j < OUT; ++j) acc[j] = bias[j];
  const float4* w4 = (const float4*)Wg + vz;
#pragma unroll 2
  for (int i = 0; i < IN; ++i) {
    float x = sIn[i];
#pragma unroll
    for (int jj = 0; jj < OUT / 4; ++jj) {
      float4 wv = w4[i * (OUT / 4) + jj];
      acc[4 * jj + 0] = fmaf(x, wv.x, acc[4 * jj + 0]);
      acc[4 * jj + 1] = fmaf(x, wv.y, acc[4 * jj + 1]);
      acc[4 * jj + 2] = fmaf(x, wv.z, acc[4 * jj + 2]);
      acc[4 * jj + 3] = fmaf(x, wv.w, acc[4 * jj + 3]);
    }
  }
}

// dense layer: input in LDS slice, weights from LDS (same-address broadcast)
template<int IN, int OUT>
__device__ __forceinline__ void layer_ls(const float* lw,                 // LDS
                                         const float* __restrict__ bias,  // global
                                         const float* sIn, float* acc) {
#pragma unroll
  for (int j = 0; j < OUT; ++j) acc[j] = bias[j];
#pragma unroll 2
  for (int i = 0; i < IN; ++i) {
    float x = sIn[i];
    const float4* w4 = (const float4*)(lw + i * OUT);
#pragma unroll
    for (int jj = 0; jj < OUT / 4; ++jj) {
      float4 wv = w4[jj];
      acc[4 * jj + 0] = fmaf(x, wv.x, acc[4 * jj + 0]);
      acc[4 * jj + 1] = fmaf(x, wv.y, acc[4 * jj + 1]);
      acc[4 * jj + 2] = fmaf(x, wv.z, acc[4 * jj + 2]);
      acc[4 * jj + 3] = fmaf(x, wv.w, acc[4 * jj + 3]);
    }
  }
}

// stable top-16 insertion (keeps lower index on ties when fed ascending j)
__device__ __forceinline__ void insert16(float d, int id, float* best, int* bidx) {
#pragma unroll
  for (int p = 0; p < KNB; ++p) {
    bool c = d < best[p];
    float tb = best[p]; int ti = bidx[p];
    best[p] = c ? d : tb; bidx[p] = c ? id : ti;
    d = c ? tb : d; id = c ? ti : id;
  }
}

// exact reference distance chain (bit-replicates f32 expanded form)
__device__ __forceinline__ float qsq(float4 qv) {
  return __fadd_rn(__fadd_rn(__fmul_rn(qv.x, qv.x), __fmul_rn(qv.y, qv.y)),
                   __fmul_rn(qv.z, qv.z));
}
__device__ __forceinline__ float refdist(float4 qv, float sq, float4 rv) {
  float sr = qsq(rv);
  float dot = __fmaf_rn(qv.z, rv.z, __fmaf_rn(qv.y, rv.y, __fmul_rn(qv.x, rv.x)));
  return __fsub_rn(__fadd_rn(sq, sr), __fadd_rn(dot, dot));
}
__device__ __forceinline__ float refdist_sr(float4 qv, float sq, float4 rv) {
  float dot = __fmaf_rn(qv.z, rv.z, __fmaf_rn(qv.y, rv.y, __fmul_rn(qv.x, rv.x)));
  return __fsub_rn(__fadd_rn(sq, rv.w), __fadd_rn(dot, dot));
}

// ---------------- dtype autodetect ----------------
__global__ void k_detect(const void* __restrict__ pts1, int* __restrict__ flag) {
  int tid = threadIdx.x;  // 64
  const bf16* p = (const bf16*)pts1;
  int cnt = 0;
  for (int i = tid; i < 1024; i += 64) {
    float v = __bfloat162float(p[i]);
    if (!(fabsf(v) <= 64.f)) cnt++;
  }
#pragma unroll
  for (int s = 32; s; s >>= 1) cnt += __shfl_down(cnt, s);
  if (tid == 0) *flag = (cnt >= 8) ? 1 : 0;
}

// ---------------- prep ----------------
struct PrepTab {
  const void* src[40];
  int off[40];
  int n[40];
  float scale[40];
};

__global__ void k_prep(PrepTab tab, float* __restrict__ W, const int* __restrict__ flag) {
  int f32 = *flag;
  int a = blockIdx.x;
  const void* s = tab.src[a];
  float* d = W + tab.off[a];
  float sc = tab.scale[a];
  for (int i = threadIdx.x; i < tab.n[a]; i += blockDim.x) d[i] = ldin(s, i, f32) * sc;
}

// ---------------- pack ----------------
__global__ void k_pack(const void* __restrict__ xyz1, const void* __restrict__ xyz2,
                       const void* __restrict__ xyz2w, const void* __restrict__ sf,
                       float4* __restrict__ pk, const int* __restrict__ flag) {
  int f32 = *flag;
  int t = blockIdx.x * 256 + threadIdx.x;  // B*N
  int b = t >> 13, n = t & (NPTS - 1);
  size_t base = (size_t)b * 3 * NPTS + n;
  float ax = ldin(xyz1, base, f32), ay = ldin(xyz1, base + NPTS, f32), az = ldin(xyz1, base + 2 * NPTS, f32);
  float sx = ldin(sf, base, f32),   sy = ldin(sf, base + NPTS, f32),   sz = ldin(sf, base + 2 * NPTS, f32);
  pk[t]          = make_float4(__fadd_rn(ax, sx), __fadd_rn(ay, sy), __fadd_rn(az, sz), 0.f);
  pk[t + BN]     = make_float4(ax, ay, az, 0.f);
  pk[t + 2 * BN] = make_float4(ldin(xyz2, base, f32), ldin(xyz2, base + NPTS, f32), ldin(xyz2, base + 2 * NPTS, f32), 0.f);
  pk[t + 3 * BN] = make_float4(ldin(xyz2w, base, f32), ldin(xyz2w, base + NPTS, f32), ldin(xyz2w, base + 2 * NPTS, f32), 0.f);
}

// ---------------- transpose ----------------
__global__ __launch_bounds__(64) void k_tr(const void* __restrict__ src, float* __restrict__ dst,
                                           const int* __restrict__ flag) {
  __shared__ float tile[64][65];
  int f32 = *flag;
  int tid = threadIdx.x;
  int n0 = blockIdx.x * 64;
  int b = blockIdx.y;
  for (int i = 0; i < 64; ++i)
    tile[i][tid] = ldin(src, ((size_t)b * 64 + i) * NPTS + n0 + tid, f32);
  __syncthreads();
  for (int i = 0; i < 64; ++i)
    dst[((size_t)b * NPTS + n0 + i) * 64 + tid] = tile[tid][i];
}

// ---------------- KNN partials: 3-phase exact top-16 ----------------
__global__ __launch_bounds__(64) void k_knnp(const float4* __restrict__ pk,
                                             int* __restrict__ part_idx) {
  __shared__ float4 tile[64];
  __shared__ int sbuf[64 * CAP];
  int tid = threadIdx.x;
  int n = blockIdx.x * 64 + tid;
  int b = blockIdx.y;
  int which = blockIdx.z >> 2;
  int part  = blockIdx.z & 3;
  const float4* q = pk + (size_t)which * BN;
  const float4* r = pk + (size_t)(2 + which) * BN + (size_t)b * NPTS;
  float4 qv = q[b * NPTS + n];
  float sq = qsq(qv);

  float best[KNB];
#pragma unroll
  for (int p = 0; p < KNB; ++p) best[p] = 3.4e38f;

  int t0 = part * (PARTC / 64);
  for (int t = t0; t < t0 + PARTC / 64; ++t) {
    __syncthreads();
    {
      float4 rv = r[t * 64 + tid];
      rv.w = qsq(rv);
      tile[tid] = rv;
    }
    __syncthreads();
#pragma unroll 8
    for (int jj = 0; jj < 64; ++jj) {
      float dd = refdist_sr(qv, sq, tile[jj]);
#pragma unroll
      for (int p = 0; p < KNB; ++p) {
        float mx = fmaxf(dd, best[p]);
        best[p] = fminf(dd, best[p]);
        dd = mx;
      }
    }
  }
  float thr = best[KNB - 1];

  int cnt = 0;
  for (int t = t0; t < t0 + PARTC / 64; ++t) {
    __syncthreads();
    {
      float4 rv = r[t * 64 + tid];
      rv.w = qsq(rv);
      tile[tid] = rv;
    }
    __syncthreads();
#pragma unroll 8
    for (int jj = 0; jj < 64; ++jj) {
      float dd = refdist_sr(qv, sq, tile[jj]);
      if (dd <= thr && cnt < CAP) {
        sbuf[tid * CAP + cnt] = t * 64 + jj;
        cnt++;
      }
    }
  }

  float bd[KNB]; int bi[KNB];
#pragma unroll
  for (int p = 0; p < KNB; ++p) { bd[p] = 3.4e38f; bi[p] = 0; }
  for (int m = 0; m < CAP; ++m) {
    if (m < cnt) {
      int id = sbuf[tid * CAP + m];
      float dd = refdist(qv, sq, r[id]);
      insert16(dd, id, bd, bi);
    }
  }
  size_t o = ((((size_t)which * BATCH + b) * NPART + part) * NPTS + n) * KNB;
#pragma unroll
  for (int p = 0; p < KNB; ++p) part_idx[o + p] = bi[p];
}

// ---------------- KNN merge ----------------
__global__ void k_merge(const float4* __restrict__ pk, const int* __restrict__ part_idx,
                        int* __restrict__ idxf) {
  int t = blockIdx.x * 256 + threadIdx.x;
  int n = t & (NPTS - 1);
  int wb = t >> 13;
  int b = wb & (BATCH - 1);
  int which = wb / BATCH;
  const float4* q = pk + (size_t)which * BN;
  const float4* r = pk + (size_t)(2 + which) * BN + (size_t)b * NPTS;
  float4 qv = q[b * NPTS + n];
  float sq = qsq(qv);
  float best[KNB]; int bidx[KNB];
#pragma unroll
  for (int p = 0; p < KNB; ++p) { best[p] = 3.4e38f; bidx[p] = 0; }
  for (int part = 0; part < NPART; ++part) {
    size_t o = ((((size_t)which * BATCH + b) * NPART + part) * NPTS + n) * KNB;
#pragma unroll
    for (int m = 0; m < KNB; ++m) {
      int id = part_idx[o + m];
      float dd = refdist(qv, sq, r[id]);
      if (dd < best[KNB - 1]) insert16(dd, id, best, bidx);
    }
  }
  size_t oo = (size_t)t * KNB;
#pragma unroll
  for (int p = 0; p < KNB; ++p) idxf[oo + p] = bidx[p];
}

// ---------------- IPC logit: x in private LDS slice, acc in regs (r8 shape),
// big weights from block LDS (same-address ds_read broadcast) ----------------
__device__ __forceinline__ float ipc_logit_lds(const float* __restrict__ W,
                                               const float* sw, float* sT,
                                               float pdx, float pdy, float pdz) {
  float acc[64];
  // ie1: 3 -> 64 (global, small)
  {
    const float* w = W + WOFF_IEW1;
    const float* bb = W + WOFF_IEB1;
    const float* g = W + WOFF_IEG;
    const float* bt = W + WOFF_IEBT;
#pragma unroll
    for (int j = 0; j < 64; ++j) {
      float v = bb[j];
      v = fmaf(pdx, w[j], v);
      v = fmaf(pdy, w[64 + j], v);
      v = fmaf(pdz, w[128 + j], v);
      v = fmaf(v, g[j], bt[j]);
      sT[j] = fmaxf(v, 0.f);
    }
  }
  layer_ls<64, 64>(sw + LW_IE2, W + WOFF_IEB2, sT, acc);
  // PEC add (weights from LDS)
  {
    const float* pb = W + WOFF_PECB;
#pragma unroll
    for (int j = 0; j < 64; ++j) acc[j] += pb[j];
    float pe[3];
    pe[0] = (pdx - rintf(pdx * 4.f) * 0.25f) * 4.f;
    pe[1] = (pdy - rintf(pdy * 4.f) * 0.25f) * 4.f;
    pe[2] = (pdz - rintf(pdz * 4.f) * 0.25f) * 4.f;
#pragma unroll
    for (int c = 0; c < 3; ++c) {
      float tt = pe[c] / 1.000001f * 6.28318530717958647692f;
#pragma unroll
      for (int f = 0; f < 4; ++f) {
        float dv = (f == 0) ? 1.f : (f == 1) ? 10.f : (f == 2) ? 100.f : 1000.f;
        float a = tt / dv;
        float sn, cs;
        sincosf(a, &sn, &cs);
        const float* ws = sw + LW_PEC + (c * 8 + f * 2) * 64;
        const float* wc = sw + LW_PEC + (c * 8 + f * 2 + 1) * 64;
#pragma unroll
        for (int j = 0; j < 64; ++j) acc[j] = fmaf(sn, ws[j], acc[j]);
#pragma unroll
        for (int j = 0; j < 64; ++j) acc[j] = fmaf(cs, wc[j], acc[j]);
      }
    }
  }
#pragma unroll
  for (int j = 0; j < 64; ++j) sT[j] = acc[j];
  layer_ls<64, 64>(sw + LW_PM1, W + WOFF_PMB1, sT, acc);
  {
    const float* g = W + WOFF_PMG1; const float* bt = W + WOFF_PMT1;
#pragma unroll
    for (int j = 0; j < 64; ++j) sT[j] = fmaxf(fmaf(acc[j], g[j], bt[j]), 0.f);
  }
  layer_ls<64, 64>(sw + LW_PM2, W + WOFF_PMB2, sT, acc);
  {
    const float* g = W + WOFF_PMG2; const float* bt = W + WOFF_PMT2;
#pragma unroll
    for (int j = 0; j < 64; ++j) sT[j] = fmaxf(fmaf(acc[j], g[j], bt[j]), 0.f);
  }
  float a3[32];
  layer_ls<64, 32>(sw + LW_PM3, W + WOFF_PMB3, sT, a3);
  {
    const float* g = W + WOFF_PMG3; const float* bt = W + WOFF_PMT3;
#pragma unroll
    for (int j = 0; j < 32; ++j) a3[j] = fmaf(a3[j], g[j], bt[j]);
  }
  const float* w4 = W + WOFF_PMW4;
  float l = W[WOFF_PMB4];
#pragma unroll
  for (int i = 0; i < 32; ++i) l = fmaf(a3[i], w4[i], l);
  return fmaf(l, W[WOFF_PMG4], W[WOFF_PMT4]);
}

// ---------------- k_logit: stage weights -> LDS; IPC + softmax -> u16 ----------------
// block = 256 threads = 16 points x 16 neighbors; which = blockIdx.y.
// LDS: 63,488 (weights) + 256*65*4 = 66,560 (x slices) = 130,048 B -> 1 block/CU.
__global__ __launch_bounds__(256, 1) void k_logit(const float* __restrict__ W,
                                                  const int* __restrict__ idxf,
                                                  const float4* __restrict__ pk,
                                                  unsigned short* __restrict__ AW) {
  __shared__ float sw[LW_TOT];
  __shared__ float sb[256 * 65];
  int tid = threadIdx.x;
  // stage big weight matrices (float4 copies; all offsets 16B-aligned)
  {
    float4* d4 = (float4*)sw;
    const float4* s_ie2 = (const float4*)(W + WOFF_IEW2);
    const float4* s_pm1 = (const float4*)(W + WOFF_PMW1);
    const float4* s_pm2 = (const float4*)(W + WOFF_PMW2);
    const float4* s_pm3 = (const float4*)(W + WOFF_PMW3);
    const float4* s_pec = (const float4*)(W + WOFF_PECW);
    for (int i = tid; i < 1024; i += 256) {
      d4[LW_IE2 / 4 + i] = s_ie2[i];
      d4[LW_PM1 / 4 + i] = s_pm1[i];
      d4[LW_PM2 / 4 + i] = s_pm2[i];
    }
    for (int i = tid; i < 512; i += 256) d4[LW_PM3 / 4 + i] = s_pm3[i];
    for (int i = tid; i < 384; i += 256) d4[LW_PEC / 4 + i] = s_pec[i];
  }
  __syncthreads();

  float* sT = sb + tid * 65;
  int k = tid & (KNB - 1);
  int p = tid >> 4;                // 0..15
  int which = blockIdx.y;
  int pt = blockIdx.x * 16 + p;    // b*N+n
  int n = pt & (NPTS - 1);
  int b = pt >> 13;
  int idxv = idxf[(((size_t)which * BATCH + b) * NPTS + n) * KNB + k];
  float4 pv = pk[(size_t)2 * BN + (size_t)b * NPTS + idxv];  // x2[idx]
  float4 qp = pk[(size_t)BN + pt];                           // x1[n]
  float l = ipc_logit_lds(W, sw, sT, pv.x - qp.x, pv.y - qp.y, pv.z - qp.z);

  float m = l;
#pragma unroll
  for (int s = 1; s < KNB; s <<= 1) m = fmaxf(m, __shfl_xor(m, s, KNB));
  float e = expf(l - m);
  float ssum = e;
#pragma unroll
  for (int s = 1; s < KNB; s <<= 1) ssum += __shfl_xor(ssum, s, KNB);
  float aw = e / ssum;
  AW[(((size_t)which * BATCH + b) * NPTS + n) * KNB + k] =
      (unsigned short)__float2uint_rn(aw * 65535.f);
}

// ---------------- k_feat: r8 structure (LDS slices + vz vector weights) ----------------
__global__ __launch_bounds__(128) void k_feat(const float* __restrict__ P1T,
                                              const float* __restrict__ P2T,
                                              const float* __restrict__ W,
                                              const int* __restrict__ idxf,
                                              const unsigned short* __restrict__ AW,
                                              const float4* __restrict__ pk,
                                              void* __restrict__ out,
                                              const int* __restrict__ flag) {
  __shared__ float sb[128 * LSTR];   // sU/sC aliased below (phases barrier-disjoint)
  float* sT = sb + (int)threadIdx.x * LSTR;
  float* sC = sb;                    // [8][132]
  float* sU = sb + 1056;             // [8][68]
  int vz = vzero();
  int f32 = *flag;
  int k = threadIdx.x & (KNB - 1);
  int p = threadIdx.x >> 4;
  int pt = blockIdx.x * 8 + p;       // b*N+n
  int n = pt & (NPTS - 1);
  int b = pt >> 13;
  float4 qp = pk[(size_t)BN + pt];   // x1[n]

  float cost[8];

  for (int which = 0; which < 2; ++which) {
    int idxv = idxf[(((size_t)which * BATCH + b) * NPTS + n) * KNB + k];
    float4 pv = pk[(size_t)2 * BN + (size_t)b * NPTS + idxv];  // x2[idx]
    float pdx = pv.x - qp.x, pdy = pv.y - qp.y, pdz = pv.z - qp.z;
    float aw = (float)AW[(((size_t)which * BATCH + b) * NPTS + n) * KNB + k] *
               (1.f / 65535.f);

    // ---- gp1 partial: lane computes channels k*4..k*4+3 ----
    {
      const float* Wa = W + (which == 0 ? WOFF_CW1A : WOFF_CW2A);
      const float* Ba = W + (which == 0 ? WOFF_CB1A : WOFF_CB2A);
      float u0 = Ba[k * 4 + 0], u1 = Ba[k * 4 + 1], u2 = Ba[k * 4 + 2], u3 = Ba[k * 4 + 3];
      const float4* p1r = (const float4*)(P1T + ((size_t)b * NPTS + n) * 64);
#define USTEP(XC, II) { float x = (XC); const float* w = Wa + (II) * 64 + k * 4; \
      u0 = fmaf(x, w[0], u0); u1 = fmaf(x, w[1], u1); \
      u2 = fmaf(x, w[2], u2); u3 = fmaf(x, w[3], u3); }
      for (int i4 = 0; i4 < 16; ++i4) {
        float4 x4 = p1r[i4];
        USTEP(x4.x, i4 * 4 + 0) USTEP(x4.y, i4 * 4 + 1)
        USTEP(x4.z, i4 * 4 + 2) USTEP(x4.w, i4 * 4 + 3)
      }
#undef USTEP
      sU[p * 68 + k * 4 + 0] = u0; sU[p * 68 + k * 4 + 1] = u1;
      sU[p * 68 + k * 4 + 2] = u2; sU[p * 68 + k * 4 + 3] = u3;
    }
    __syncthreads();

    float acc[64];
#pragma unroll
    for (int j = 0; j < 64; ++j) acc[j] = sU[p * 68 + j];
    __syncthreads();   // sU aliased into sb: consume before sT writes

    // ---- gp2 side of layer-a: broadcast vector-load weights ----
    {
      const float4* w4a = (const float4*)(W + (which == 0 ? WOFF_CW1A : WOFF_CW2A) + 64 * 64) + vz;
      const float4* p2r = (const float4*)(P2T + ((size_t)b * NPTS + idxv) * 64);
#define GSTEP(XC, II) { float x = (XC); \
      _Pragma("unroll") for (int jj = 0; jj < 16; ++jj) { \
        float4 wv = w4a[(II) * 16 + jj]; \
        acc[4 * jj + 0] = fmaf(x, wv.x, acc[4 * jj + 0]); \
        acc[4 * jj + 1] = fmaf(x, wv.y, acc[4 * jj + 1]); \
        acc[4 * jj + 2] = fmaf(x, wv.z, acc[4 * jj + 2]); \
        acc[4 * jj + 3] = fmaf(x, wv.w, acc[4 * jj + 3]); } }
      for (int i4 = 0; i4 < 16; ++i4) {
        float4 x4 = p2r[i4];
        GSTEP(x4.x, i4 * 4 + 0) GSTEP(x4.y, i4 * 4 + 1)
        GSTEP(x4.z, i4 * 4 + 2) GSTEP(x4.w, i4 * 4 + 3)
      }
#undef GSTEP
    }
#pragma unroll
    for (int j = 0; j < 64; ++j) sT[j] = lrelu(acc[j]);
    if (which == 0) {
      layer_gv<64, 64>(W + WOFF_CW1B, W + WOFF_CB1B, sT, acc, vz);
    } else {
      layer_gv<64, 64>(W + WOFF_CW2B, W + WOFF_CB2B, sT, acc, vz);
      sT[0] = pdx; sT[1] = pdy; sT[2] = pdz;
#pragma unroll
      for (int j = 0; j < 64; ++j) sT[3 + j] = lrelu(acc[j]);
      layer_gv<67, 64>(W + WOFF_CW3A, W + WOFF_CB3A, sT, acc, vz);
#pragma unroll
      for (int j = 0; j < 64; ++j) sT[j] = lrelu(acc[j]);
      layer_gv<64, 64>(W + WOFF_CW3B, W + WOFF_CB3B, sT, acc, vz);
    }

    // ---- scaled row to LDS, transpose-reduce over the 16 neighbors ----
#pragma unroll
    for (int j = 0; j < 64; ++j) sT[j] = lrelu(acc[j]) * aw;
    __syncthreads();
    float o0 = 0.f, o1 = 0.f, o2 = 0.f, o3 = 0.f;
#pragma unroll
    for (int kk = 0; kk < KNB; ++kk) {
      const float* row = sb + (p * KNB + kk) * LSTR + k * 4;
      o0 += row[0]; o1 += row[1]; o2 += row[2]; o3 += row[3];
    }
    cost[which * 4 + 0] = o0; cost[which * 4 + 1] = o1;
    cost[which * 4 + 2] = o2; cost[which * 4 + 3] = o3;
    __syncthreads();
  }

  // ---- chain4: [costA | costB] -> 64 -> 64 ----
#pragma unroll
  for (int q = 0; q < 4; ++q) {
    sC[p * 132 + k * 4 + q] = cost[q];
    sC[p * 132 + 64 + k * 4 + q] = cost[4 + q];
  }
  __syncthreads();
  float a4[4];
  {
    const float* W4 = W + WOFF_CW4A;
    const float* B4 = W + WOFF_CB4A;
#pragma unroll
    for (int q = 0; q < 4; ++q) a4[q] = B4[k * 4 + q];
    for (int i = 0; i < 128; ++i) {
      float x = sC[p * 132 + i];
      const float* w = W4 + i * 64 + k * 4;
#pragma unroll
      for (int q = 0; q < 4; ++q) a4[q] = fmaf(x, w[q], a4[q]);
    }
  }
  __syncthreads();
#pragma unroll
  for (int q = 0; q < 4; ++q) sU[p * 68 + k * 4 + q] = lrelu(a4[q]);
  __syncthreads();
  {
    const float* W4 = W + WOFF_CW4B;
    const float* B4 = W + WOFF_CB4B;
#pragma unroll
    for (int q = 0; q < 4; ++q) a4[q] = B4[k * 4 + q];
    for (int i = 0; i < 64; ++i) {
      float x = sU[p * 68 + i];
      const float* w = W4 + i * 64 + k * 4;
#pragma unroll
      for (int q = 0; q < 4; ++q) a4[q] = fmaf(x, w[q], a4[q]);
    }
  }
  size_t ob = (size_t)b * 64 * NPTS + n;
#pragma unroll
  for (int q = 0; q < 4; ++q)
    stout(out, ob + (size_t)(k * 4 + q) * NPTS, lrelu(a4[q]), f32);
}

// ---------------- host ----------------
extern "C" void kernel_launch(void* const* d_in, const int* in_sizes, int n_in,
                              void* d_out, int out_size, void* d_ws, size_t ws_size,
                              hipStream_t stream) {
  (void)in_sizes; (void)n_in; (void)out_size; (void)ws_size;
  float*  W    = (float*)d_ws;
  int*    FLAG = (int*)((char*)d_ws + BOFF_FLAG);
  float4* PK   = (float4*)((char*)d_ws + BOFF_PK);
  int*    IDX  = (int*)((char*)d_ws + BOFF_IDX);
  unsigned short* AW = (unsigned short*)((char*)d_ws + BOFF_AW);
  float*  P1T  = (float*)((char*)d_ws + BOFF_P1T);
  float*  P2T  = (float*)((char*)d_ws + BOFF_P2T);
  int*    PART = (int*)((char*)d_ws + BOFF_PART);

  static const int WOFFS[40] = {
    WOFF_CW1A, WOFF_CB1A, WOFF_CW1B, WOFF_CB1B,
    WOFF_CW2A, WOFF_CB2A, WOFF_CW2B, WOFF_CB2B,
    WOFF_CW3A, WOFF_CB3A, WOFF_CW3B, WOFF_CB3B,
    WOFF_CW4A, WOFF_CB4A, WOFF_CW4B, WOFF_CB4B,
    WOFF_IEW1, WOFF_IEB1, WOFF_IEG,  WOFF_IEBT,
    WOFF_IEW2, WOFF_IEB2, WOFF_PECW, WOFF_PECB,
    WOFF_PMW1, WOFF_PMB1, WOFF_PMG1, WOFF_PMT1,
    WOFF_PMW2, WOFF_PMB2, WOFF_PMG2, WOFF_PMT2,
    WOFF_PMW3, WOFF_PMB3, WOFF_PMG3, WOFF_PMT3,
    WOFF_PMW4, WOFF_PMB4, WOFF_PMG4, WOFF_PMT4};
  static const int WNS[40] = {
    8192, 64, 4096, 64,  8192, 64, 4096, 64,  4288, 64, 4096, 64,
    8192, 64, 4096, 64,  192, 64, 64, 64,  4096, 64,  1536, 64,
    4096, 64, 64, 64,  4096, 64, 64, 64,  2048, 32, 32, 32,  32, 1, 1, 1};

  PrepTab tab;
  for (int a = 0; a < 40; ++a) {
    tab.src[a] = d_in[6 + a];
    tab.off[a] = WOFFS[a];
    tab.n[a] = WNS[a];
    tab.scale[a] = 1.f;
  }
  tab.scale[18] = C_IE;                               // ie_g
  tab.scale[26] = C_PM; tab.scale[30] = C_PM;         // pm_g1, pm_g2
  tab.scale[34] = C_PM; tab.scale[38] = C_PM;         // pm_g3, pm_g4

  k_detect<<<dim3(1), dim3(64), 0, stream>>>(d_in[3], FLAG);
  k_prep<<<dim3(40), dim3(256), 0, stream>>>(tab, W, FLAG);
  k_pack<<<dim3(64), dim3(256), 0, stream>>>(d_in[0], d_in[1], d_in[2], d_in[5], PK, FLAG);
  k_knnp<<<dim3(NPTS / 64, BATCH, 2 * NPART), dim3(64), 0, stream>>>(PK, PART);
  k_merge<<<dim3(2 * BN / 256), dim3(256), 0, stream>>>(PK, PART, IDX);
  // transposes AFTER merge: PART aliases P1T/P2T
  k_tr<<<dim3(NPTS / 64, BATCH), dim3(64), 0, stream>>>(d_in[3], P1T, FLAG);
  k_tr<<<dim3(NPTS / 64, BATCH), dim3(64), 0, stream>>>(d_in[4], P2T, FLAG);
  k_logit<<<dim3(BN / 16, 2), dim3(256), 0, stream>>>(W, IDX, PK, AW);
  k_feat<<<dim3(BN / 8), dim3(128), 0, stream>>>(P1T, P2T, W, IDX, AW, PK, d_out, FLAG);
}

// Round 13
// 2438.270 us; speedup vs baseline: 2.9125x; 1.3551x over previous
//
#include <hip/hip_runtime.h>
#include <hip/hip_bf16.h>
#include <math.h>

typedef __hip_bfloat16 bf16;

#define NPTS  8192
#define BATCH 2
#define KNB   16
#define NPART 4
#define PARTC (NPTS / NPART)   // 2048
#define CAP   24               // knn pass-2 capture buffer per thread
#define LSTR  69               // k_feat per-thread LDS slice stride
#define BN    (BATCH * NPTS)

#define C_IE 0.9999950000374997f   // 1/sqrt(1+1e-5)
#define C_PM 0.9995003746877732f   // 1/sqrt(1+1e-3)

// ---- weight block float offsets inside ws ----
enum {
  WOFF_CW1A = 0,     WOFF_CB1A = 8192,  WOFF_CW1B = 8256,  WOFF_CB1B = 12352,
  WOFF_CW2A = 12416, WOFF_CB2A = 20608, WOFF_CW2B = 20672, WOFF_CB2B = 24768,
  WOFF_CW3A = 24832, WOFF_CB3A = 29120, WOFF_CW3B = 29184, WOFF_CB3B = 33280,
  WOFF_CW4A = 33344, WOFF_CB4A = 41536, WOFF_CW4B = 41600, WOFF_CB4B = 45696,
  WOFF_IEW1 = 45760, WOFF_IEB1 = 45952, WOFF_IEG  = 46016, WOFF_IEBT = 46080,
  WOFF_IEW2 = 46144, WOFF_IEB2 = 50240, WOFF_PECW = 50304, WOFF_PECB = 51840,
  WOFF_PMW1 = 51904, WOFF_PMB1 = 56000, WOFF_PMG1 = 56064, WOFF_PMT1 = 56128,
  WOFF_PMW2 = 56192, WOFF_PMB2 = 60288, WOFF_PMG2 = 60352, WOFF_PMT2 = 60416,
  WOFF_PMW3 = 60480, WOFF_PMB3 = 62528, WOFF_PMG3 = 62560, WOFF_PMT3 = 62592,
  WOFF_PMW4 = 62624, WOFF_PMB4 = 62656, WOFF_PMG4 = 62657, WOFF_PMT4 = 62658
};

// ---- ws byte offsets (end 13,893,648 B == round-6..8 footprint, known good) ----
#define BOFF_W    0u
#define BOFF_FLAG 262144u
#define BOFF_PK   262160u     // 4 x [B*N] float4 (2 MB)
#define BOFF_IDX  2359312u    // final idx [2][B][N][16] i32 (2 MB)
#define BOFF_AW   4456464u    // attention weights u16 [2][B][N][16] (1 MB)
#define BOFF_P1T  5505040u    // points1^T [B][N][64] f32 (4 MB)
#define BOFF_P2T  9699344u    // points2^T [B][N][64] f32 (4 MB)
#define BOFF_PART BOFF_P1T    // knn partials aliased over P1T/P2T; k_tr after k_merge

__device__ __forceinline__ float lrelu(float v) { return v > 0.f ? v : 0.1f * v; }

__device__ __forceinline__ float ldin(const void* p, size_t i, int f32) {
  return f32 ? ((const float*)p)[i] : __bfloat162float(((const bf16*)p)[i]);
}
__device__ __forceinline__ void stout(void* p, size_t i, float v, int f32) {
  if (f32) ((float*)p)[i] = v;
  else ((bf16*)p)[i] = __float2bfloat16(v);
}

// opaque per-lane zero -> forces vector (global_load) addressing of weights,
// pipelined via in-order vmcnt (s_load serializes; LDS-weights spill -- r9..r12)
__device__ __forceinline__ int vzero() {
  int vz;
  asm volatile("v_mov_b32 %0, 0" : "=v"(vz));
  return vz;
}

// dense layer: input in LDS slice, weights via broadcast vector loads
template<int IN, int OUT>
__device__ __forceinline__ void layer_gv(const float* __restrict__ Wg,
                                         const float* __restrict__ bias,
                                         const float* sIn, float* acc, int vz) {
#pragma unroll
  for (int j = 0; j < OUT; ++j) acc[j] = bias[j];
  const float4* w4 = (const float4*)Wg + vz;
#pragma unroll 2
  for (int i = 0; i < IN; ++i) {
    float x = sIn[i];
#pragma unroll
    for (int jj = 0; jj < OUT / 4; ++jj) {
      float4 wv = w4[i * (OUT / 4) + jj];
      acc[4 * jj + 0] = fmaf(x, wv.x, acc[4 * jj + 0]);
      acc[4 * jj + 1] = fmaf(x, wv.y, acc[4 * jj + 1]);
      acc[4 * jj + 2] = fmaf(x, wv.z, acc[4 * jj + 2]);
      acc[4 * jj + 3] = fmaf(x, wv.w, acc[4 * jj + 3]);
    }
  }
}

// stable top-16 insertion (keeps lower index on ties when fed ascending j)
__device__ __forceinline__ void insert16(float d, int id, float* best, int* bidx) {
#pragma unroll
  for (int p = 0; p < KNB; ++p) {
    bool c = d < best[p];
    float tb = best[p]; int ti = bidx[p];
    best[p] = c ? d : tb; bidx[p] = c ? id : ti;
    d = c ? tb : d; id = c ? ti : id;
  }
}

// exact reference distance chain (bit-replicates f32 expanded form)
__device__ __forceinline__ float qsq(float4 qv) {
  return __fadd_rn(__fadd_rn(__fmul_rn(qv.x, qv.x), __fmul_rn(qv.y, qv.y)),
                   __fmul_rn(qv.z, qv.z));
}
__device__ __forceinline__ float refdist(float4 qv, float sq, float4 rv) {
  float sr = qsq(rv);
  float dot = __fmaf_rn(qv.z, rv.z, __fmaf_rn(qv.y, rv.y, __fmul_rn(qv.x, rv.x)));
  return __fsub_rn(__fadd_rn(sq, sr), __fadd_rn(dot, dot));
}
__device__ __forceinline__ float refdist_sr(float4 qv, float sq, float4 rv) {
  float dot = __fmaf_rn(qv.z, rv.z, __fmaf_rn(qv.y, rv.y, __fmul_rn(qv.x, rv.x)));
  return __fsub_rn(__fadd_rn(sq, rv.w), __fadd_rn(dot, dot));
}

// ---------------- dtype autodetect ----------------
__global__ void k_detect(const void* __restrict__ pts1, int* __restrict__ flag) {
  int tid = threadIdx.x;  // 64
  const bf16* p = (const bf16*)pts1;
  int cnt = 0;
  for (int i = tid; i < 1024; i += 64) {
    float v = __bfloat162float(p[i]);
    if (!(fabsf(v) <= 64.f)) cnt++;
  }
#pragma unroll
  for (int s = 32; s; s >>= 1) cnt += __shfl_down(cnt, s);
  if (tid == 0) *flag = (cnt >= 8) ? 1 : 0;
}

// ---------------- prep ----------------
struct PrepTab {
  const void* src[40];
  int off[40];
  int n[40];
  float scale[40];
};

__global__ void k_prep(PrepTab tab, float* __restrict__ W, const int* __restrict__ flag) {
  int f32 = *flag;
  int a = blockIdx.x;
  const void* s = tab.src[a];
  float* d = W + tab.off[a];
  float sc = tab.scale[a];
  for (int i = threadIdx.x; i < tab.n[a]; i += blockDim.x) d[i] = ldin(s, i, f32) * sc;
}

// ---------------- pack ----------------
__global__ void k_pack(const void* __restrict__ xyz1, const void* __restrict__ xyz2,
                       const void* __restrict__ xyz2w, const void* __restrict__ sf,
                       float4* __restrict__ pk, const int* __restrict__ flag) {
  int f32 = *flag;
  int t = blockIdx.x * 256 + threadIdx.x;  // B*N
  int b = t >> 13, n = t & (NPTS - 1);
  size_t base = (size_t)b * 3 * NPTS + n;
  float ax = ldin(xyz1, base, f32), ay = ldin(xyz1, base + NPTS, f32), az = ldin(xyz1, base + 2 * NPTS, f32);
  float sx = ldin(sf, base, f32),   sy = ldin(sf, base + NPTS, f32),   sz = ldin(sf, base + 2 * NPTS, f32);
  pk[t]          = make_float4(__fadd_rn(ax, sx), __fadd_rn(ay, sy), __fadd_rn(az, sz), 0.f);
  pk[t + BN]     = make_float4(ax, ay, az, 0.f);
  pk[t + 2 * BN] = make_float4(ldin(xyz2, base, f32), ldin(xyz2, base + NPTS, f32), ldin(xyz2, base + 2 * NPTS, f32), 0.f);
  pk[t + 3 * BN] = make_float4(ldin(xyz2w, base, f32), ldin(xyz2w, base + NPTS, f32), ldin(xyz2w, base + 2 * NPTS, f32), 0.f);
}

// ---------------- transpose ----------------
__global__ __launch_bounds__(64) void k_tr(const void* __restrict__ src, float* __restrict__ dst,
                                           const int* __restrict__ flag) {
  __shared__ float tile[64][65];
  int f32 = *flag;
  int tid = threadIdx.x;
  int n0 = blockIdx.x * 64;
  int b = blockIdx.y;
  for (int i = 0; i < 64; ++i)
    tile[i][tid] = ldin(src, ((size_t)b * 64 + i) * NPTS + n0 + tid, f32);
  __syncthreads();
  for (int i = 0; i < 64; ++i)
    dst[((size_t)b * NPTS + n0 + i) * 64 + tid] = tile[tid][i];
}

// ---------------- KNN partials: 3-phase exact top-16 over one part ----------------
__global__ __launch_bounds__(64) void k_knnp(const float4* __restrict__ pk,
                                             int* __restrict__ part_idx) {
  __shared__ float4 tile[64];
  __shared__ int sbuf[64 * CAP];
  int tid = threadIdx.x;
  int n = blockIdx.x * 64 + tid;
  int b = blockIdx.y;
  int which = blockIdx.z >> 2;   // NPART==4
  int part  = blockIdx.z & 3;
  const float4* q = pk + (size_t)which * BN;
  const float4* r = pk + (size_t)(2 + which) * BN + (size_t)b * NPTS;
  float4 qv = q[b * NPTS + n];
  float sq = qsq(qv);

  float best[KNB];
#pragma unroll
  for (int p = 0; p < KNB; ++p) best[p] = 3.4e38f;

  int t0 = part * (PARTC / 64);
  // pass 1: exact 16 smallest distance VALUES (branch-free sorted network)
  for (int t = t0; t < t0 + PARTC / 64; ++t) {
    __syncthreads();
    {
      float4 rv = r[t * 64 + tid];
      rv.w = qsq(rv);
      tile[tid] = rv;
    }
    __syncthreads();
#pragma unroll 8
    for (int jj = 0; jj < 64; ++jj) {
      float dd = refdist_sr(qv, sq, tile[jj]);
#pragma unroll
      for (int p = 0; p < KNB; ++p) {
        float mx = fmaxf(dd, best[p]);
        best[p] = fminf(dd, best[p]);
        dd = mx;
      }
    }
  }
  float thr = best[KNB - 1];

  // pass 2: capture candidate indices with dd <= thr
  int cnt = 0;
  for (int t = t0; t < t0 + PARTC / 64; ++t) {
    __syncthreads();
    {
      float4 rv = r[t * 64 + tid];
      rv.w = qsq(rv);
      tile[tid] = rv;
    }
    __syncthreads();
#pragma unroll 8
    for (int jj = 0; jj < 64; ++jj) {
      float dd = refdist_sr(qv, sq, tile[jj]);
      if (dd <= thr && cnt < CAP) {
        sbuf[tid * CAP + cnt] = t * 64 + jj;
        cnt++;
      }
    }
  }

  // post: exact (d, idx) selection among <=CAP captured
  float bd[KNB]; int bi[KNB];
#pragma unroll
  for (int p = 0; p < KNB; ++p) { bd[p] = 3.4e38f; bi[p] = 0; }
  for (int m = 0; m < CAP; ++m) {
    if (m < cnt) {
      int id = sbuf[tid * CAP + m];
      float dd = refdist(qv, sq, r[id]);
      insert16(dd, id, bd, bi);
    }
  }
  size_t o = ((((size_t)which * BATCH + b) * NPART + part) * NPTS + n) * KNB;
#pragma unroll
  for (int p = 0; p < KNB; ++p) part_idx[o + p] = bi[p];
}

// ---------------- KNN merge ----------------
__global__ void k_merge(const float4* __restrict__ pk, const int* __restrict__ part_idx,
                        int* __restrict__ idxf) {
  int t = blockIdx.x * 256 + threadIdx.x;  // (which*B+b)*N+n
  int n = t & (NPTS - 1);
  int wb = t >> 13;
  int b = wb & (BATCH - 1);
  int which = wb / BATCH;
  const float4* q = pk + (size_t)which * BN;
  const float4* r = pk + (size_t)(2 + which) * BN + (size_t)b * NPTS;
  float4 qv = q[b * NPTS + n];
  float sq = qsq(qv);
  float best[KNB]; int bidx[KNB];
#pragma unroll
  for (int p = 0; p < KNB; ++p) { best[p] = 3.4e38f; bidx[p] = 0; }
  for (int part = 0; part < NPART; ++part) {
    size_t o = ((((size_t)which * BATCH + b) * NPART + part) * NPTS + n) * KNB;
#pragma unroll
    for (int m = 0; m < KNB; ++m) {
      int id = part_idx[o + m];
      float dd = refdist(qv, sq, r[id]);
      if (dd < best[KNB - 1]) insert16(dd, id, best, bidx);
    }
  }
  size_t oo = (size_t)t * KNB;
#pragma unroll
  for (int p = 0; p < KNB; ++p) idxf[oo + p] = bidx[p];
}

// ---------------- IPC logit (r8: LDS slice x, global vz weights, acc in regs) ----------------
__device__ __forceinline__ float ipc_logit(const float* __restrict__ W, float* sT,
                                           float pdx, float pdy, float pdz, int vz) {
  float acc[64];
  {
    const float* w = W + WOFF_IEW1;
    const float* bb = W + WOFF_IEB1;
    const float* g = W + WOFF_IEG;
    const float* bt = W + WOFF_IEBT;
#pragma unroll
    for (int j = 0; j < 64; ++j) {
      float v = bb[j];
      v = fmaf(pdx, w[j], v);
      v = fmaf(pdy, w[64 + j], v);
      v = fmaf(pdz, w[128 + j], v);
      v = fmaf(v, g[j], bt[j]);
      sT[j] = fmaxf(v, 0.f);
    }
  }
  layer_gv<64, 64>(W + WOFF_IEW2, W + WOFF_IEB2, sT, acc, vz);
  {
    const float* pw = W + WOFF_PECW;
    const float* pb = W + WOFF_PECB;
#pragma unroll
    for (int j = 0; j < 64; ++j) acc[j] += pb[j];
    float pe[3];
    pe[0] = (pdx - rintf(pdx * 4.f) * 0.25f) * 4.f;
    pe[1] = (pdy - rintf(pdy * 4.f) * 0.25f) * 4.f;
    pe[2] = (pdz - rintf(pdz * 4.f) * 0.25f) * 4.f;
#pragma unroll
    for (int c = 0; c < 3; ++c) {
      float tt = pe[c] / 1.000001f * 6.28318530717958647692f;
#pragma unroll
      for (int f = 0; f < 4; ++f) {
        float dv = (f == 0) ? 1.f : (f == 1) ? 10.f : (f == 2) ? 100.f : 1000.f;
        float a = tt / dv;
        float sn, cs;
        sincosf(a, &sn, &cs);
        const float* ws = pw + (c * 8 + f * 2) * 64;
        const float* wc = pw + (c * 8 + f * 2 + 1) * 64;
#pragma unroll
        for (int j = 0; j < 64; ++j) acc[j] = fmaf(sn, ws[j], acc[j]);
#pragma unroll
        for (int j = 0; j < 64; ++j) acc[j] = fmaf(cs, wc[j], acc[j]);
      }
    }
  }
#pragma unroll
  for (int j = 0; j < 64; ++j) sT[j] = acc[j];
  layer_gv<64, 64>(W + WOFF_PMW1, W + WOFF_PMB1, sT, acc, vz);
  {
    const float* g = W + WOFF_PMG1; const float* bt = W + WOFF_PMT1;
#pragma unroll
    for (int j = 0; j < 64; ++j) sT[j] = fmaxf(fmaf(acc[j], g[j], bt[j]), 0.f);
  }
  layer_gv<64, 64>(W + WOFF_PMW2, W + WOFF_PMB2, sT, acc, vz);
  {
    const float* g = W + WOFF_PMG2; const float* bt = W + WOFF_PMT2;
#pragma unroll
    for (int j = 0; j < 64; ++j) sT[j] = fmaxf(fmaf(acc[j], g[j], bt[j]), 0.f);
  }
  float a3[32];
  layer_gv<64, 32>(W + WOFF_PMW3, W + WOFF_PMB3, sT, a3, vz);
  {
    const float* g = W + WOFF_PMG3; const float* bt = W + WOFF_PMT3;
#pragma unroll
    for (int j = 0; j < 32; ++j) a3[j] = fmaf(a3[j], g[j], bt[j]);
  }
  const float* w4 = W + WOFF_PMW4;
  float l = W[WOFF_PMB4];
#pragma unroll
  for (int i = 0; i < 32; ++i) l = fmaf(a3[i], w4[i], l);
  return fmaf(l, W[WOFF_PMG4], W[WOFF_PMT4]);
}

// ---------------- k_logit: IPC + 16-lane softmax -> u16 attention weights ----------------
__global__ __launch_bounds__(64) void k_logit(const float* __restrict__ W,
                                              const int* __restrict__ idxf,
                                              const float4* __restrict__ pk,
                                              unsigned short* __restrict__ AW) {
  __shared__ float sb[64 * 65];
  float* sT = sb + (int)threadIdx.x * 65;
  int vz = vzero();
  int k = threadIdx.x & (KNB - 1);
  int p = threadIdx.x >> 4;
  int which = blockIdx.y;
  int pt = blockIdx.x * 4 + p;       // b*N+n
  int n = pt & (NPTS - 1);
  int b = pt >> 13;
  int idxv = idxf[(((size_t)which * BATCH + b) * NPTS + n) * KNB + k];
  float4 pv = pk[(size_t)2 * BN + (size_t)b * NPTS + idxv];  // x2[idx]
  float4 qp = pk[(size_t)BN + pt];                           // x1[n]
  float l = ipc_logit(W, sT, pv.x - qp.x, pv.y - qp.y, pv.z - qp.z, vz);

  float m = l;
#pragma unroll
  for (int s = 1; s < KNB; s <<= 1) m = fmaxf(m, __shfl_xor(m, s, KNB));
  float e = expf(l - m);
  float ssum = e;
#pragma unroll
  for (int s = 1; s < KNB; s <<= 1) ssum += __shfl_xor(ssum, s, KNB);
  float aw = e / ssum;
  AW[(((size_t)which * BATCH + b) * NPTS + n) * KNB + k] =
      (unsigned short)__float2uint_rn(aw * 65535.f);
}

// ---------------- k_feat: chains + weighted sums + chain4 + output ----------------
__global__ __launch_bounds__(128) void k_feat(const float* __restrict__ P1T,
                                              const float* __restrict__ P2T,
                                              const float* __restrict__ W,
                                              const int* __restrict__ idxf,
                                              const unsigned short* __restrict__ AW,
                                              const float4* __restrict__ pk,
                                              void* __restrict__ out,
                                              const int* __restrict__ flag) {
  __shared__ float sb[128 * LSTR];   // sU/sC aliased below (phases barrier-disjoint)
  float* sT = sb + (int)threadIdx.x * LSTR;
  float* sC = sb;                    // [8][132]
  float* sU = sb + 1056;             // [8][68]
  int vz = vzero();
  int f32 = *flag;
  int k = threadIdx.x & (KNB - 1);
  int p = threadIdx.x >> 4;
  int pt = blockIdx.x * 8 + p;       // b*N+n
  int n = pt & (NPTS - 1);
  int b = pt >> 13;
  float4 qp = pk[(size_t)BN + pt];   // x1[n]

  float cost[8];

  for (int which = 0; which < 2; ++which) {
    int idxv = idxf[(((size_t)which * BATCH + b) * NPTS + n) * KNB + k];
    float4 pv = pk[(size_t)2 * BN + (size_t)b * NPTS + idxv];  // x2[idx]
    float pdx = pv.x - qp.x, pdy = pv.y - qp.y, pdz = pv.z - qp.z;
    float aw = (float)AW[(((size_t)which * BATCH + b) * NPTS + n) * KNB + k] *
               (1.f / 65535.f);

    // ---- gp1 partial: lane computes channels k*4..k*4+3 ----
    {
      const float* Wa = W + (which == 0 ? WOFF_CW1A : WOFF_CW2A);
      const float* Ba = W + (which == 0 ? WOFF_CB1A : WOFF_CB2A);
      float u0 = Ba[k * 4 + 0], u1 = Ba[k * 4 + 1], u2 = Ba[k * 4 + 2], u3 = Ba[k * 4 + 3];
      const float4* p1r = (const float4*)(P1T + ((size_t)b * NPTS + n) * 64);
#define USTEP(XC, II) { float x = (XC); const float* w = Wa + (II) * 64 + k * 4; \
      u0 = fmaf(x, w[0], u0); u1 = fmaf(x, w[1], u1); \
      u2 = fmaf(x, w[2], u2); u3 = fmaf(x, w[3], u3); }
      for (int i4 = 0; i4 < 16; ++i4) {
        float4 x4 = p1r[i4];
        USTEP(x4.x, i4 * 4 + 0) USTEP(x4.y, i4 * 4 + 1)
        USTEP(x4.z, i4 * 4 + 2) USTEP(x4.w, i4 * 4 + 3)
      }
#undef USTEP
      sU[p * 68 + k * 4 + 0] = u0; sU[p * 68 + k * 4 + 1] = u1;
      sU[p * 68 + k * 4 + 2] = u2; sU[p * 68 + k * 4 + 3] = u3;
    }
    __syncthreads();

    float acc[64];
#pragma unroll
    for (int j = 0; j < 64; ++j) acc[j] = sU[p * 68 + j];
    __syncthreads();   // sU aliased into sb: consume before sT writes

    // ---- gp2 side of layer-a: broadcast vector-load weights ----
    {
      const float4* w4a = (const float4*)(W + (which == 0 ? WOFF_CW1A : WOFF_CW2A) + 64 * 64) + vz;
      const float4* p2r = (const float4*)(P2T + ((size_t)b * NPTS + idxv) * 64);
#define GSTEP(XC, II) { float x = (XC); \
      _Pragma("unroll") for (int jj = 0; jj < 16; ++jj) { \
        float4 wv = w4a[(II) * 16 + jj]; \
        acc[4 * jj + 0] = fmaf(x, wv.x, acc[4 * jj + 0]); \
        acc[4 * jj + 1] = fmaf(x, wv.y, acc[4 * jj + 1]); \
        acc[4 * jj + 2] = fmaf(x, wv.z, acc[4 * jj + 2]); \
        acc[4 * jj + 3] = fmaf(x, wv.w, acc[4 * jj + 3]); } }
      for (int i4 = 0; i4 < 16; ++i4) {
        float4 x4 = p2r[i4];
        GSTEP(x4.x, i4 * 4 + 0) GSTEP(x4.y, i4 * 4 + 1)
        GSTEP(x4.z, i4 * 4 + 2) GSTEP(x4.w, i4 * 4 + 3)
      }
#undef GSTEP
    }
#pragma unroll
    for (int j = 0; j < 64; ++j) sT[j] = lrelu(acc[j]);
    if (which == 0) {
      layer_gv<64, 64>(W + WOFF_CW1B, W + WOFF_CB1B, sT, acc, vz);
    } else {
      layer_gv<64, 64>(W + WOFF_CW2B, W + WOFF_CB2B, sT, acc, vz);
      sT[0] = pdx; sT[1] = pdy; sT[2] = pdz;
#pragma unroll
      for (int j = 0; j < 64; ++j) sT[3 + j] = lrelu(acc[j]);
      layer_gv<67, 64>(W + WOFF_CW3A, W + WOFF_CB3A, sT, acc, vz);
#pragma unroll
      for (int j = 0; j < 64; ++j) sT[j] = lrelu(acc[j]);
      layer_gv<64, 64>(W + WOFF_CW3B, W + WOFF_CB3B, sT, acc, vz);
    }

    // ---- scaled row to LDS, transpose-reduce over the 16 neighbors ----
#pragma unroll
    for (int j = 0; j < 64; ++j) sT[j] = lrelu(acc[j]) * aw;
    __syncthreads();
    float o0 = 0.f, o1 = 0.f, o2 = 0.f, o3 = 0.f;
#pragma unroll
    for (int kk = 0; kk < KNB; ++kk) {
      const float* row = sb + (p * KNB + kk) * LSTR + k * 4;
      o0 += row[0]; o1 += row[1]; o2 += row[2]; o3 += row[3];
    }
    cost[which * 4 + 0] = o0; cost[which * 4 + 1] = o1;
    cost[which * 4 + 2] = o2; cost[which * 4 + 3] = o3;
    __syncthreads();
  }

  // ---- chain4: [costA | costB] -> 64 -> 64 ----
#pragma unroll
  for (int q = 0; q < 4; ++q) {
    sC[p * 132 + k * 4 + q] = cost[q];
    sC[p * 132 + 64 + k * 4 + q] = cost[4 + q];
  }
  __syncthreads();
  float a4[4];
  {
    const float* W4 = W + WOFF_CW4A;
    const float* B4 = W + WOFF_CB4A;
#pragma unroll
    for (int q = 0; q < 4; ++q) a4[q] = B4[k * 4 + q];
    for (int i = 0; i < 128; ++i) {
      float x = sC[p * 132 + i];
      const float* w = W4 + i * 64 + k * 4;
#pragma unroll
      for (int q = 0; q < 4; ++q) a4[q] = fmaf(x, w[q], a4[q]);
    }
  }
  __syncthreads();
#pragma unroll
  for (int q = 0; q < 4; ++q) sU[p * 68 + k * 4 + q] = lrelu(a4[q]);
  __syncthreads();
  {
    const float* W4 = W + WOFF_CW4B;
    const float* B4 = W + WOFF_CB4B;
#pragma unroll
    for (int q = 0; q < 4; ++q) a4[q] = B4[k * 4 + q];
    for (int i = 0; i < 64; ++i) {
      float x = sU[p * 68 + i];
      const float* w = W4 + i * 64 + k * 4;
#pragma unroll
      for (int q = 0; q < 4; ++q) a4[q] = fmaf(x, w[q], a4[q]);
    }
  }
  size_t ob = (size_t)b * 64 * NPTS + n;
#pragma unroll
  for (int q = 0; q < 4; ++q)
    stout(out, ob + (size_t)(k * 4 + q) * NPTS, lrelu(a4[q]), f32);
}

// ---------------- host ----------------
extern "C" void kernel_launch(void* const* d_in, const int* in_sizes, int n_in,
                              void* d_out, int out_size, void* d_ws, size_t ws_size,
                              hipStream_t stream) {
  (void)in_sizes; (void)n_in; (void)out_size; (void)ws_size;
  float*  W    = (float*)d_ws;
  int*    FLAG = (int*)((char*)d_ws + BOFF_FLAG);
  float4* PK   = (float4*)((char*)d_ws + BOFF_PK);
  int*    IDX  = (int*)((char*)d_ws + BOFF_IDX);
  unsigned short* AW = (unsigned short*)((char*)d_ws + BOFF_AW);
  float*  P1T  = (float*)((char*)d_ws + BOFF_P1T);
  float*  P2T  = (float*)((char*)d_ws + BOFF_P2T);
  int*    PART = (int*)((char*)d_ws + BOFF_PART);

  static const int WOFFS[40] = {
    WOFF_CW1A, WOFF_CB1A, WOFF_CW1B, WOFF_CB1B,
    WOFF_CW2A, WOFF_CB2A, WOFF_CW2B, WOFF_CB2B,
    WOFF_CW3A, WOFF_CB3A, WOFF_CW3B, WOFF_CB3B,
    WOFF_CW4A, WOFF_CB4A, WOFF_CW4B, WOFF_CB4B,
    WOFF_IEW1, WOFF_IEB1, WOFF_IEG,  WOFF_IEBT,
    WOFF_IEW2, WOFF_IEB2, WOFF_PECW, WOFF_PECB,
    WOFF_PMW1, WOFF_PMB1, WOFF_PMG1, WOFF_PMT1,
    WOFF_PMW2, WOFF_PMB2, WOFF_PMG2, WOFF_PMT2,
    WOFF_PMW3, WOFF_PMB3, WOFF_PMG3, WOFF_PMT3,
    WOFF_PMW4, WOFF_PMB4, WOFF_PMG4, WOFF_PMT4};
  static const int WNS[40] = {
    8192, 64, 4096, 64,  8192, 64, 4096, 64,  4288, 64, 4096, 64,
    8192, 64, 4096, 64,  192, 64, 64, 64,  4096, 64,  1536, 64,
    4096, 64, 64, 64,  4096, 64, 64, 64,  2048, 32, 32, 32,  32, 1, 1, 1};

  PrepTab tab;
  for (int a = 0; a < 40; ++a) {
    tab.src[a] = d_in[6 + a];
    tab.off[a] = WOFFS[a];
    tab.n[a] = WNS[a];
    tab.scale[a] = 1.f;
  }
  tab.scale[18] = C_IE;                               // ie_g
  tab.scale[26] = C_PM; tab.scale[30] = C_PM;         // pm_g1, pm_g2
  tab.scale[34] = C_PM; tab.scale[38] = C_PM;         // pm_g3, pm_g4

  k_detect<<<dim3(1), dim3(64), 0, stream>>>(d_in[3], FLAG);
  k_prep<<<dim3(40), dim3(256), 0, stream>>>(tab, W, FLAG);
  k_pack<<<dim3(64), dim3(256), 0, stream>>>(d_in[0], d_in[1], d_in[2], d_in[5], PK, FLAG);
  k_knnp<<<dim3(NPTS / 64, BATCH, 2 * NPART), dim3(64), 0, stream>>>(PK, PART);
  k_merge<<<dim3(2 * BN / 256), dim3(256), 0, stream>>>(PK, PART, IDX);
  // transposes AFTER merge: PART aliases P1T/P2T
  k_tr<<<dim3(NPTS / 64, BATCH), dim3(64), 0, stream>>>(d_in[3], P1T, FLAG);
  k_tr<<<dim3(NPTS / 64, BATCH), dim3(64), 0, stream>>>(d_in[4], P2T, FLAG);
  k_logit<<<dim3(BN / 4, 2), dim3(64), 0, stream>>>(W, IDX, PK, AW);
  k_feat<<<dim3(BN / 8), dim3(128), 0, stream>>>(P1T, P2T, W, IDX, AW, PK, d_out, FLAG);
}